// Round 9
// baseline (518.057 us; speedup 1.0000x reference)
//
#include <hip/hip_runtime.h>

// MACE layer, fp32 I/O. N=20000, E=320000, F=64, P=5, R=8, H=64, S=10.
// R9: receiver-sorted segmented reduction for the edge scatter.
//   kprep    : bucketing + weight swizzles + zero deg[]
//   khist    : deg[rcv]++ per edge
//   knodeA2  : zero Ah + s1/v1 MFMA GEMM; block 313 = exclusive scan deg->cursor
//   kscatter : counting-sort edges by receiver -> order[]
//   kedge3   : per wave 64 sorted edges (4 sub-tiles of 16): radial MLP ->
//              MFMA tw-GEMM -> TP -> fp32 segment accumulate, packed-fp16
//              atomic flush only on receiver change (~25k segments vs 320k edges)
//   knodeC2  : unchanged (MFMA + species-sorted tiles)
#define NNODES 20000
#define NEDGES 320000
#define NTILES 1260

typedef __attribute__((ext_vector_type(8))) short short8;    // 8 bf16
typedef __attribute__((ext_vector_type(4))) float float4v;   // 16 B
typedef _Float16 half2v __attribute__((ext_vector_type(2))); // packed fp16

// fragment-pool chunk offsets (1 chunk = 8 bf16 = 16 B)
#define CW2   0
#define CWls  2560
#define CWlv  3072
#define CWis  3584
#define CWiv  4096
#define CWps  4608
#define CWpv  5120
#define CWss  5632
#define CWsv  10752
#define NCHUNK_TOT 15872     // 2560 + 6*512 + 2*5120

__device__ __forceinline__ float bitsf(unsigned u){ union{unsigned u; float f;} x; x.u=u; return x.f; }
__device__ __forceinline__ float b2f(unsigned short u){ return bitsf(((unsigned)u)<<16); }
__device__ __forceinline__ unsigned short f2b(float f){
    union{float f; unsigned u;} x; x.f=f;
    unsigned r = x.u + 0x7fffu + ((x.u>>16)&1u);   // RNE
    return (unsigned short)(r>>16);
}
__device__ __forceinline__ short8 pack8(const float* f){
    short8 r;
    #pragma unroll
    for (int j=0;j<8;++j) r[j] = (short)f2b(f[j]);
    return r;
}

__constant__ float kINV_SQRT3 = 0.5773502691896258f;
__constant__ float kINV_SQRT2 = 0.7071067811865476f;
__constant__ float kINV_AVG   = 0.25f;             // 1/sqrt(16)

// ---- merged prep: bucketing (block 0) + all weight swizzles (blocks 1..62) + zero deg ---
__global__ __launch_bounds__(256) void kprep(
    const int* __restrict__ specie,
    const float* __restrict__ Wr2,
    const float* __restrict__ Wls, const float* __restrict__ Wlv,
    const float* __restrict__ Wis, const float* __restrict__ Wiv,
    const float* __restrict__ Wps, const float* __restrict__ Wpv,
    const float* __restrict__ Wss, const float* __restrict__ Wsv,
    unsigned short* __restrict__ P,
    int* __restrict__ perm, int* __restrict__ tspec,
    int* __restrict__ deg)
{
    const int tid = threadIdx.x;
    // zero the edge-degree histogram (consumed by khist, next dispatch)
    for (int i = blockIdx.x*256 + tid; i < NNODES; i += 63*256) deg[i] = 0;

    if (blockIdx.x == 0){
        __shared__ int cnt[10], base[10], ntl[10], cur[10];
        if (tid < 10) cnt[tid] = 0;
        __syncthreads();
        for (int n = tid; n < NNODES; n += 256) atomicAdd(&cnt[specie[n]], 1);
        __syncthreads();
        if (tid == 0){
            int b = 0;
            for (int sp = 0; sp < 10; ++sp){
                base[sp] = b; cur[sp] = b;
                ntl[sp] = (cnt[sp] + 15) >> 4;
                b += ntl[sp] << 4;
            }
        }
        __syncthreads();
        for (int i = tid; i < NTILES*16; i += 256) perm[i] = -1;
        for (int t = tid; t < NTILES; t += 256){
            int sp = 0;
            #pragma unroll
            for (int k = 0; k < 10; ++k)
                if (t >= (base[k] >> 4) && t < (base[k] >> 4) + ntl[k]) sp = k;
            tspec[t] = sp;
        }
        __syncthreads();
        for (int n = tid; n < NNODES; n += 256){
            int slot = atomicAdd(&cur[specie[n]], 1);
            perm[slot] = n;
        }
        return;
    }
    const int c = (blockIdx.x - 1)*256 + tid;
    if (c >= NCHUNK_TOT) return;
    unsigned short t[8];
    if (c < 2560){
        const int nt = c >> 7, ks = (c >> 6) & 1, ln = c & 63;
        const int col = nt*16 + (ln & 15);
        const int jb  = ks*32 + ((ln >> 4) & 3)*8;
        #pragma unroll
        for (int jj = 0; jj < 8; ++jj) t[jj] = f2b(Wr2[(jb+jj)*320 + col]);
    } else {
        int c2 = c - 2560;
        const float* src;
        if      (c2 <  512){ src = Wls; }
        else if (c2 < 1024){ src = Wlv; c2 -= 512; }
        else if (c2 < 1536){ src = Wis; c2 -= 1024; }
        else if (c2 < 2048){ src = Wiv; c2 -= 1536; }
        else if (c2 < 2560){ src = Wps; c2 -= 2048; }
        else if (c2 < 3072){ src = Wpv; c2 -= 2560; }
        else if (c2 < 8192){ src = Wss; c2 -= 3072; }
        else               { src = Wsv; c2 -= 8192; }
        const int grp = c2 >> 9, loc = c2 & 511;
        const int nt = loc >> 7, ks = (loc >> 6) & 1, ln = loc & 63;
        const int col  = nt*16 + (ln & 15);
        const int row0 = grp*64 + ks*32 + ((ln>>4)&3)*8;
        #pragma unroll
        for (int jj = 0; jj < 8; ++jj) t[jj] = f2b(src[(row0+jj)*64 + col]);
    }
    unsigned* d = (unsigned*)(P + (size_t)c*8);
    d[0] = (unsigned)t[0] | ((unsigned)t[1]<<16);
    d[1] = (unsigned)t[2] | ((unsigned)t[3]<<16);
    d[2] = (unsigned)t[4] | ((unsigned)t[5]<<16);
    d[3] = (unsigned)t[6] | ((unsigned)t[7]<<16);
}

// ---- edge-degree histogram ---------------------------------------------------------------
__global__ __launch_bounds__(256) void khist(
    const int* __restrict__ receivers, int* __restrict__ deg)
{
    const int e = blockIdx.x*256 + threadIdx.x;
    if (e < NEDGES) atomicAdd(&deg[receivers[e]], 1);
}

// ---- counting-sort scatter ---------------------------------------------------------------
__global__ __launch_bounds__(256) void kscatter(
    const int* __restrict__ receivers, int* __restrict__ cursor, int* __restrict__ order)
{
    const int e = blockIdx.x*256 + threadIdx.x;
    if (e < NEDGES){
        int r = receivers[e];
        int p = atomicAdd(&cursor[r], 1);
        order[p] = e;
    }
}

// ---- Kernel A (MFMA): zero Ah + s1/v1 GEMM; block 313 = deg->cursor exclusive scan ------
__global__ __launch_bounds__(256) void knodeA2(
    const float* __restrict__ s, const float* __restrict__ v,
    const unsigned short* __restrict__ P,
    unsigned short* __restrict__ s1, unsigned short* __restrict__ v1,
    float4v* __restrict__ AhZ,
    const int* __restrict__ deg, int* __restrict__ cursor)
{
    if (blockIdx.x == 313){
        __shared__ int lsum[256], loff[256];
        const int t = threadIdx.x;
        const int start = t*79;
        const int end = (start + 79 < NNODES) ? start + 79 : NNODES;
        int sum = 0;
        for (int i = start; i < end; ++i) sum += deg[i];
        lsum[t] = sum;
        __syncthreads();
        if (t == 0){
            int run = 0;
            for (int k = 0; k < 256; ++k){ loff[k] = run; run += lsum[k]; }
        }
        __syncthreads();
        int run = loff[t];
        for (int i = start; i < end; ++i){ cursor[i] = run; run += deg[i]; }
        return;
    }
    // zero the fp16 accumulator (NNODES*128 dwords = 640000 float4)
    float4v zz = {0.f,0.f,0.f,0.f};
    for (int i = blockIdx.x*256 + threadIdx.x; i < NNODES*32; i += 313*256) AhZ[i] = zz;

    const int w = threadIdx.x >> 6, lane = threadIdx.x & 63;
    const int t = blockIdx.x*4 + w;
    if (t >= 1250) return;
    const int mcol = lane & 15, quad = lane >> 4;
    const int node = t*16 + mcol;
    const short8* PB = (const short8*)P;

    short8 fS[2], fV[3][2];
    #pragma unroll
    for (int ks = 0; ks < 2; ++ks){
        const int k0 = ks*32 + quad*8;
        float ts[8];
        { float4v a = *(const float4v*)&s[node*64 + k0];
          float4v b = *(const float4v*)&s[node*64 + k0 + 4];
          #pragma unroll
          for (int j = 0; j < 4; ++j){ ts[j] = a[j]; ts[4+j] = b[j]; } }
        fS[ks] = pack8(ts);
        float tv[24];
        #pragma unroll
        for (int q = 0; q < 6; ++q){
            float4v x = *(const float4v*)&v[(node*64 + k0)*3 + q*4];
            #pragma unroll
            for (int j = 0; j < 4; ++j) tv[q*4+j] = x[j];
        }
        #pragma unroll
        for (int c = 0; c < 3; ++c){
            float tc[8];
            #pragma unroll
            for (int j = 0; j < 8; ++j) tc[j] = tv[j*3 + c];
            fV[c][ks] = pack8(tc);
        }
    }
    float4v z = {0.f,0.f,0.f,0.f};
    #pragma unroll
    for (int nt = 0; nt < 4; ++nt){
        float4v aS = __builtin_amdgcn_mfma_f32_16x16x32_bf16(fS[0], PB[CWls+(nt*2+0)*64+lane], z, 0,0,0);
        aS = __builtin_amdgcn_mfma_f32_16x16x32_bf16(fS[1], PB[CWls+(nt*2+1)*64+lane], aS, 0,0,0);
        float4v aV[3];
        #pragma unroll
        for (int c = 0; c < 3; ++c){
            aV[c] = __builtin_amdgcn_mfma_f32_16x16x32_bf16(fV[c][0], PB[CWlv+(nt*2+0)*64+lane], z, 0,0,0);
            aV[c] = __builtin_amdgcn_mfma_f32_16x16x32_bf16(fV[c][1], PB[CWlv+(nt*2+1)*64+lane], aV[c], 0,0,0);
        }
        const int g = nt*16 + mcol;
        #pragma unroll
        for (int r = 0; r < 4; ++r){
            const int nr = t*16 + quad*4 + r;
            s1[nr*64 + g] = f2b(aS[r]);
            #pragma unroll
            for (int c = 0; c < 3; ++c) v1[(nr*3+c)*64 + g] = f2b(aV[c][r]);
        }
    }
}

// ---- Kernel B (R9): 64 sorted edges/wave, segmented fp32 accumulate + fp16 atomic flush --
__global__ __launch_bounds__(256) void kedge3(
    const float* __restrict__ Y1, const float* __restrict__ ef,
    const int* __restrict__ senders, const int* __restrict__ receivers,
    const int* __restrict__ order,
    const float* __restrict__ Wr1, const unsigned short* __restrict__ W2s,
    const unsigned short* __restrict__ s1, const unsigned short* __restrict__ v1,
    half2v* __restrict__ Ah)
{
    __shared__ unsigned short hlds[64*72];
    __shared__ unsigned short twlds[64*330];
    const int lane = threadIdx.x & 63;
    const int w    = threadIdx.x >> 6;
    float w1r[8];
    #pragma unroll
    for (int r = 0; r < 8; ++r) w1r[r] = Wr1[r*64 + lane];

    int cur = -1;
    float aS = 0.f, a0 = 0.f, a1 = 0.f, a2 = 0.f;

    for (int kt = 0; kt < 4; ++kt){
        const int base = blockIdx.x*256 + w*64 + kt*16;   // 16 sorted edges
        int oreg   = (lane < 16) ? order[base + lane] : 0;
        int sndreg = (lane < 16) ? senders[oreg]   : 0;
        int rcvreg = (lane < 16) ? receivers[oreg] : 0;
        float yreg = (lane < 48) ? Y1[__shfl(oreg, lane & 15)*3 + (lane >> 4)] : 0.f;
        int ea = __shfl(oreg, lane >> 3);
        int eb = __shfl(oreg, 8 + (lane >> 3));
        float ef0 = ef[ea*8 + (lane & 7)];
        float ef1 = ef[eb*8 + (lane & 7)];

        // radial layer 1 -> h rows (wave-private LDS slice; no barrier needed)
        #pragma unroll
        for (int e16 = 0; e16 < 16; ++e16){
            float src = (e16 < 8) ? ef0 : ef1;
            float hj = 0.f;
            #pragma unroll
            for (int r = 0; r < 8; ++r) hj += __shfl(src, (e16&7)*8 + r) * w1r[r];
            hj = hj / (1.f + __expf(-hj));
            hlds[(w*16 + e16)*72 + lane] = f2b(hj);
        }

        // MFMA tw-GEMM: tw[16,320] = h[16,64] @ W2[64,320]
        short8 fa0 = *(const short8*)&hlds[(w*16 + (lane&15))*72 +      (lane>>4)*8];
        short8 fa1 = *(const short8*)&hlds[(w*16 + (lane&15))*72 + 32 + (lane>>4)*8];
        float4v acc[20];
        #pragma unroll
        for (int nt = 0; nt < 20; ++nt){
            short8 b0 = *(const short8*)&W2s[((nt*2+0)*64 + lane)*8];
            short8 b1 = *(const short8*)&W2s[((nt*2+1)*64 + lane)*8];
            float4v z = {0.f, 0.f, 0.f, 0.f};
            acc[nt] = __builtin_amdgcn_mfma_f32_16x16x32_bf16(fa0, b0, z, 0, 0, 0);
            acc[nt] = __builtin_amdgcn_mfma_f32_16x16x32_bf16(fa1, b1, acc[nt], 0, 0, 0);
        }
        #pragma unroll
        for (int nt = 0; nt < 20; ++nt){
            const int col = nt*16 + (lane & 15);
            #pragma unroll
            for (int r = 0; r < 4; ++r){
                const int erow = w*16 + (lane>>4)*4 + r;
                twlds[erow*330 + col] = f2b(acc[nt][r]);
            }
        }

        // TP + segmented accumulate (rcv is wave-uniform per e16; sorted order)
        for (int e16 = 0; e16 < 16; ++e16){
            const int erow = w*16 + e16;
            float tw0 = b2f(twlds[erow*330 +   0 + lane]);
            float tw1 = b2f(twlds[erow*330 +  64 + lane]);
            float tw2 = b2f(twlds[erow*330 + 128 + lane]);
            float tw3 = b2f(twlds[erow*330 + 192 + lane]);
            float tw4 = b2f(twlds[erow*330 + 256 + lane]);
            const int snd = __shfl(sndreg, e16);
            const int rcv = __shfl(rcvreg, e16);
            float y0 = __shfl(yreg, e16);
            float y1 = __shfl(yreg, 16 + e16);
            float y2 = __shfl(yreg, 32 + e16);
            float ss  = b2f(s1[snd*64 + lane]);
            float vs0 = b2f(v1[(snd*3+0)*64 + lane]);
            float vs1 = b2f(v1[(snd*3+1)*64 + lane]);
            float vs2 = b2f(v1[(snd*3+2)*64 + lane]);
            float dot = vs0*y0 + vs1*y1 + vs2*y2;
            float c0 = vs1*y2 - vs2*y1;
            float c1 = vs2*y0 - vs0*y2;
            float c2 = vs0*y1 - vs1*y0;
            float ms  = tw0*ss + tw1*dot*kINV_SQRT3;
            float t2s = tw2*ss, t4 = tw4*kINV_SQRT2;
            float mv0 = t2s*y0 + tw3*vs0 + t4*c0;
            float mv1 = t2s*y1 + tw3*vs1 + t4*c1;
            float mv2 = t2s*y2 + tw3*vs2 + t4*c2;
            if (rcv != cur){
                if (cur >= 0){
                    half2v p01 = { (_Float16)aS, (_Float16)a0 };
                    half2v p23 = { (_Float16)a1, (_Float16)a2 };
                    __builtin_amdgcn_global_atomic_fadd_v2f16(&Ah[cur*128 + lane],      p01);
                    __builtin_amdgcn_global_atomic_fadd_v2f16(&Ah[cur*128 + 64 + lane], p23);
                }
                cur = rcv; aS = ms; a0 = mv0; a1 = mv1; a2 = mv2;
            } else {
                aS += ms; a0 += mv0; a1 += mv1; a2 += mv2;
            }
        }
    }
    if (cur >= 0){
        half2v p01 = { (_Float16)aS, (_Float16)a0 };
        half2v p23 = { (_Float16)a1, (_Float16)a2 };
        __builtin_amdgcn_global_atomic_fadd_v2f16(&Ah[cur*128 + lane],      p01);
        __builtin_amdgcn_global_atomic_fadd_v2f16(&Ah[cur*128 + 64 + lane], p23);
    }
}

// ---- Kernel C (MFMA, species-sorted tiles; vectorized gathers) --------------------------
__global__ __launch_bounds__(256) void knodeC2(
    const float* __restrict__ s, const float* __restrict__ v,
    const half2v* __restrict__ Ah,
    const unsigned short* __restrict__ P,
    const int* __restrict__ perm, const int* __restrict__ tspec,
    const float* __restrict__ wps, const float* __restrict__ wpv,
    const float* __restrict__ Wread,
    float* __restrict__ out)
{
    __shared__ unsigned short Bt[4][4][16*72];
    const int w = threadIdx.x >> 6, lane = threadIdx.x & 63;
    const int t = blockIdx.x*4 + w;
    if (t >= NTILES) return;
    const int mcol = lane & 15, quad = lane >> 4;
    const int spec = tspec[t];
    const int nA   = perm[t*16 + mcol];
    const short8* PB = (const short8*)P;
    const int sb = CWss + spec*512, vb = CWsv + spec*512;

    short8 fAs[2], fAv[3][2], fS[2], fV[3][2];
    if (nA >= 0){
        #pragma unroll
        for (int ks = 0; ks < 2; ++ks){
            const int k0 = ks*32 + quad*8;
            half2v pa[8], pb[8];
            *(float4v*)&pa[0] = *(const float4v*)&Ah[nA*128 + k0];
            *(float4v*)&pa[4] = *(const float4v*)&Ah[nA*128 + k0 + 4];
            *(float4v*)&pb[0] = *(const float4v*)&Ah[nA*128 + 64 + k0];
            *(float4v*)&pb[4] = *(const float4v*)&Ah[nA*128 + 64 + k0 + 4];
            float as_[8], a0_[8], a1_[8], a2_[8];
            #pragma unroll
            for (int j = 0; j < 8; ++j){
                as_[j] = (float)pa[j].x; a0_[j] = (float)pa[j].y;
                a1_[j] = (float)pb[j].x; a2_[j] = (float)pb[j].y;
            }
            fAs[ks] = pack8(as_); fAv[0][ks] = pack8(a0_);
            fAv[1][ks] = pack8(a1_); fAv[2][ks] = pack8(a2_);
            float ts[8];
            { float4v a = *(const float4v*)&s[nA*64 + k0];
              float4v b = *(const float4v*)&s[nA*64 + k0 + 4];
              #pragma unroll
              for (int j = 0; j < 4; ++j){ ts[j] = a[j]; ts[4+j] = b[j]; } }
            fS[ks] = pack8(ts);
            float tv[24];
            #pragma unroll
            for (int q = 0; q < 6; ++q){
                float4v x = *(const float4v*)&v[(nA*64 + k0)*3 + q*4];
                #pragma unroll
                for (int j = 0; j < 4; ++j) tv[q*4+j] = x[j];
            }
            #pragma unroll
            for (int c = 0; c < 3; ++c){
                float tc[8];
                #pragma unroll
                for (int j = 0; j < 8; ++j) tc[j] = tv[j*3 + c];
                fV[c][ks] = pack8(tc);
            }
        }
    } else {
        short8 z8 = {};
        #pragma unroll
        for (int ks = 0; ks < 2; ++ks){
            fAs[ks] = z8; fS[ks] = z8;
            #pragma unroll
            for (int c = 0; c < 3; ++c){ fAv[c][ks] = z8; fV[c][ks] = z8; }
        }
    }

    float4v z = {0.f,0.f,0.f,0.f};
    float4v scS[4], scV[3][4];
    #pragma unroll
    for (int nt = 0; nt < 4; ++nt){
        float4v Ais = __builtin_amdgcn_mfma_f32_16x16x32_bf16(fAs[0], PB[CWis+(nt*2+0)*64+lane], z, 0,0,0);
        Ais = __builtin_amdgcn_mfma_f32_16x16x32_bf16(fAs[1], PB[CWis+(nt*2+1)*64+lane], Ais, 0,0,0);
        float4v Aiv[3];
        #pragma unroll
        for (int c = 0; c < 3; ++c){
            Aiv[c] = __builtin_amdgcn_mfma_f32_16x16x32_bf16(fAv[c][0], PB[CWiv+(nt*2+0)*64+lane], z, 0,0,0);
            Aiv[c] = __builtin_amdgcn_mfma_f32_16x16x32_bf16(fAv[c][1], PB[CWiv+(nt*2+1)*64+lane], Aiv[c], 0,0,0);
        }
        scS[nt] = __builtin_amdgcn_mfma_f32_16x16x32_bf16(fS[0], PB[sb+(nt*2+0)*64+lane], z, 0,0,0);
        scS[nt] = __builtin_amdgcn_mfma_f32_16x16x32_bf16(fS[1], PB[sb+(nt*2+1)*64+lane], scS[nt], 0,0,0);
        #pragma unroll
        for (int c = 0; c < 3; ++c){
            scV[c][nt] = __builtin_amdgcn_mfma_f32_16x16x32_bf16(fV[c][0], PB[vb+(nt*2+0)*64+lane], z, 0,0,0);
            scV[c][nt] = __builtin_amdgcn_mfma_f32_16x16x32_bf16(fV[c][1], PB[vb+(nt*2+1)*64+lane], scV[c][nt], 0,0,0);
        }
        const int g = nt*16 + mcol;
        float w0 = wps[spec*320 +   0 + g], w1 = wps[spec*320 +  64 + g];
        float w2 = wps[spec*320 + 128 + g], w3 = wps[spec*320 + 192 + g];
        float w4 = wps[spec*320 + 256 + g];
        float u0 = wpv[spec*256 +   0 + g], u1 = wpv[spec*256 +  64 + g];
        float u2 = wpv[spec*256 + 128 + g], u3 = wpv[spec*256 + 192 + g];
        #pragma unroll
        for (int r = 0; r < 4; ++r){
            float A  = Ais[r]    * kINV_AVG;
            float a0 = Aiv[0][r] * kINV_AVG;
            float a1 = Aiv[1][r] * kINV_AVG;
            float a2 = Aiv[2][r] * kINV_AVG;
            float d   = a0*a0 + a1*a1 + a2*a2;
            float as2 = A*A;
            float Bs  = w0*A + w1*as2 + w2*d + w3*as2*A + w4*A*d;
            float gg  = u0 + u1*A + u2*as2 + u3*d;
            const int row = quad*4 + r;
            Bt[w][0][row*72 + g] = f2b(Bs);
            Bt[w][1][row*72 + g] = f2b(gg*a0);
            Bt[w][2][row*72 + g] = f2b(gg*a1);
            Bt[w][3][row*72 + g] = f2b(gg*a2);
        }
    }

    short8 bS[2], bV[3][2];
    #pragma unroll
    for (int ks = 0; ks < 2; ++ks){
        bS[ks] = *(const short8*)&Bt[w][0][mcol*72 + ks*32 + quad*8];
        #pragma unroll
        for (int c = 0; c < 3; ++c)
            bV[c][ks] = *(const short8*)&Bt[w][1+c][mcol*72 + ks*32 + quad*8];
    }

    float* out_node = out;
    float* out_s    = out + NNODES;
    float* out_v    = out + NNODES + NNODES*64;
    int ndr[4];
    #pragma unroll
    for (int r = 0; r < 4; ++r) ndr[r] = perm[t*16 + quad*4 + r];
    float4v rd = {0.f,0.f,0.f,0.f};
    #pragma unroll
    for (int nt = 0; nt < 4; ++nt){
        float4v oS = scS[nt];
        oS = __builtin_amdgcn_mfma_f32_16x16x32_bf16(bS[0], PB[CWps+(nt*2+0)*64+lane], oS, 0,0,0);
        oS = __builtin_amdgcn_mfma_f32_16x16x32_bf16(bS[1], PB[CWps+(nt*2+1)*64+lane], oS, 0,0,0);
        float4v oV[3];
        #pragma unroll
        for (int c = 0; c < 3; ++c){
            oV[c] = scV[c][nt];
            oV[c] = __builtin_amdgcn_mfma_f32_16x16x32_bf16(bV[c][0], PB[CWpv+(nt*2+0)*64+lane], oV[c], 0,0,0);
            oV[c] = __builtin_amdgcn_mfma_f32_16x16x32_bf16(bV[c][1], PB[CWpv+(nt*2+1)*64+lane], oV[c], 0,0,0);
        }
        const int g = nt*16 + mcol;
        float wr = Wread[g];
        #pragma unroll
        for (int r = 0; r < 4; ++r){
            if (ndr[r] >= 0){
                out_s[ndr[r]*64 + g] = oS[r];
                #pragma unroll
                for (int c = 0; c < 3; ++c) out_v[(ndr[r]*64 + g)*3 + c] = oV[c][r];
            }
            rd[r] += oS[r] * wr;
        }
    }
    #pragma unroll
    for (int off = 1; off < 16; off <<= 1){
        #pragma unroll
        for (int r = 0; r < 4; ++r) rd[r] += __shfl_xor(rd[r], off);
    }
    if (mcol == 0){
        #pragma unroll
        for (int r = 0; r < 4; ++r) if (ndr[r] >= 0) out_node[ndr[r]] = rd[r];
    }
}

extern "C" void kernel_launch(void* const* d_in, const int* in_sizes, int n_in,
                              void* d_out, int out_size, void* d_ws, size_t ws_size,
                              hipStream_t stream)
{
    (void)in_sizes; (void)n_in; (void)out_size; (void)ws_size;
    const float* s    = (const float*)d_in[0];
    const float* v    = (const float*)d_in[1];
    const float* Y1   = (const float*)d_in[2];
    const float* ef   = (const float*)d_in[3];
    const int* specie = (const int*)d_in[4];
    const int* senders   = (const int*)d_in[5];
    const int* receivers = (const int*)d_in[6];
    const float* Wls  = (const float*)d_in[7];
    const float* Wlv  = (const float*)d_in[8];
    const float* Wss  = (const float*)d_in[9];
    const float* Wsv  = (const float*)d_in[10];
    const float* Wr1  = (const float*)d_in[11];
    const float* Wr2  = (const float*)d_in[12];
    const float* Wis  = (const float*)d_in[13];
    const float* Wiv  = (const float*)d_in[14];
    const float* wps  = (const float*)d_in[15];
    const float* wpv  = (const float*)d_in[16];
    const float* Wps  = (const float*)d_in[17];
    const float* Wpv  = (const float*)d_in[18];
    const float* Wrd  = (const float*)d_in[19];

    float* out = (float*)d_out;
    unsigned short* t_s1 = (unsigned short*)(out + NNODES);   // bf16 temp in d_out
    unsigned short* t_v1 = t_s1 + NNODES*64;

    // ws layout:
    //  [0, 253952)            bf16 fragment pool P
    //  [262144, +10.24M)      Ah fp16 accumulator [N][2][64] half2
    //  [10502144, +80640)     perm[20160]
    //  [10582784, +5040)      tspec[1260]
    //  [10587824, +80000)     deg[20000]
    //  [10667824, +80000)     cursor[20000]
    //  [10747824, +1280000)   order[320000]
    char* ws = (char*)d_ws;
    unsigned short* P = (unsigned short*)ws;
    half2v* Ah  = (half2v*)(ws + 262144);
    int* perm   = (int*)(ws + 10502144);
    int* tspec  = (int*)(ws + 10582784);
    int* deg    = (int*)(ws + 10587824);
    int* cursor = (int*)(ws + 10667824);
    int* order  = (int*)(ws + 10747824);

    kprep<<<63, 256, 0, stream>>>(specie, Wr2, Wls, Wlv, Wis, Wiv, Wps, Wpv, Wss, Wsv,
                                  P, perm, tspec, deg);
    khist<<<1250, 256, 0, stream>>>(receivers, deg);
    knodeA2<<<314, 256, 0, stream>>>(s, v, P, t_s1, t_v1, (float4v*)Ah, deg, cursor);
    kscatter<<<1250, 256, 0, stream>>>(receivers, cursor, order);
    kedge3<<<1250, 256, 0, stream>>>(Y1, ef, senders, receivers, order, Wr1, P + CW2*8,
                                     t_s1, t_v1, Ah);
    knodeC2<<<315, 256, 0, stream>>>(s, v, Ah, P, perm, tspec, wps, wpv, Wrd, out);
}

// Round 10
// 361.641 us; speedup vs baseline: 1.4325x; 1.4325x over previous
//
#include <hip/hip_runtime.h>

// MACE layer, fp32 I/O. N=20000, E=320000, F=64, P=5, R=8, H=64, S=10.
// R10: receiver-sorted edges with MATERIALIZED sorted inputs (fixes R9's
// occupancy collapse + scattered-fetch blowup):
//   kprep   : bucketing + weight swizzles + zero deg[]
//   khist   : deg[rcv]++
//   knodeA2 : zero Ah + s1/v1 MFMA GEMM; block 313 = exclusive scan deg->cursor
//   kgather : counting-sort scatter that WRITES sorted efs(bf16)/ys/snds
//             (into d_out's free tail) and rcvs (ws) -> kedge4 loads coalesced
//   kedge4  : kedge2's exact shape (16 edges/wave) + 5-reg fp32 segment
//             accumulator, packed-fp16 atomic flush on receiver change only
//   knodeC2 : unchanged (MFMA + species-sorted tiles)
#define NNODES 20000
#define NEDGES 320000
#define NTILES 1260

typedef __attribute__((ext_vector_type(8))) short short8;    // 8 bf16
typedef __attribute__((ext_vector_type(4))) float float4v;   // 16 B
typedef _Float16 half2v __attribute__((ext_vector_type(2))); // packed fp16

// fragment-pool chunk offsets (1 chunk = 8 bf16 = 16 B)
#define CW2   0
#define CWls  2560
#define CWlv  3072
#define CWis  3584
#define CWiv  4096
#define CWps  4608
#define CWpv  5120
#define CWss  5632
#define CWsv  10752
#define NCHUNK_TOT 15872     // 2560 + 6*512 + 2*5120

__device__ __forceinline__ float bitsf(unsigned u){ union{unsigned u; float f;} x; x.u=u; return x.f; }
__device__ __forceinline__ float b2f(unsigned short u){ return bitsf(((unsigned)u)<<16); }
__device__ __forceinline__ unsigned short f2b(float f){
    union{float f; unsigned u;} x; x.f=f;
    unsigned r = x.u + 0x7fffu + ((x.u>>16)&1u);   // RNE
    return (unsigned short)(r>>16);
}
__device__ __forceinline__ short8 pack8(const float* f){
    short8 r;
    #pragma unroll
    for (int j=0;j<8;++j) r[j] = (short)f2b(f[j]);
    return r;
}

__constant__ float kINV_SQRT3 = 0.5773502691896258f;
__constant__ float kINV_SQRT2 = 0.7071067811865476f;
__constant__ float kINV_AVG   = 0.25f;             // 1/sqrt(16)

// ---- merged prep: bucketing (block 0) + all weight swizzles (blocks 1..62) + zero deg ---
__global__ __launch_bounds__(256) void kprep(
    const int* __restrict__ specie,
    const float* __restrict__ Wr2,
    const float* __restrict__ Wls, const float* __restrict__ Wlv,
    const float* __restrict__ Wis, const float* __restrict__ Wiv,
    const float* __restrict__ Wps, const float* __restrict__ Wpv,
    const float* __restrict__ Wss, const float* __restrict__ Wsv,
    unsigned short* __restrict__ P,
    int* __restrict__ perm, int* __restrict__ tspec,
    int* __restrict__ deg)
{
    const int tid = threadIdx.x;
    for (int i = blockIdx.x*256 + tid; i < NNODES; i += 63*256) deg[i] = 0;

    if (blockIdx.x == 0){
        __shared__ int cnt[10], base[10], ntl[10], cur[10];
        if (tid < 10) cnt[tid] = 0;
        __syncthreads();
        for (int n = tid; n < NNODES; n += 256) atomicAdd(&cnt[specie[n]], 1);
        __syncthreads();
        if (tid == 0){
            int b = 0;
            for (int sp = 0; sp < 10; ++sp){
                base[sp] = b; cur[sp] = b;
                ntl[sp] = (cnt[sp] + 15) >> 4;
                b += ntl[sp] << 4;
            }
        }
        __syncthreads();
        for (int i = tid; i < NTILES*16; i += 256) perm[i] = -1;
        for (int t = tid; t < NTILES; t += 256){
            int sp = 0;
            #pragma unroll
            for (int k = 0; k < 10; ++k)
                if (t >= (base[k] >> 4) && t < (base[k] >> 4) + ntl[k]) sp = k;
            tspec[t] = sp;
        }
        __syncthreads();
        for (int n = tid; n < NNODES; n += 256){
            int slot = atomicAdd(&cur[specie[n]], 1);
            perm[slot] = n;
        }
        return;
    }
    const int c = (blockIdx.x - 1)*256 + tid;
    if (c >= NCHUNK_TOT) return;
    unsigned short t[8];
    if (c < 2560){
        const int nt = c >> 7, ks = (c >> 6) & 1, ln = c & 63;
        const int col = nt*16 + (ln & 15);
        const int jb  = ks*32 + ((ln >> 4) & 3)*8;
        #pragma unroll
        for (int jj = 0; jj < 8; ++jj) t[jj] = f2b(Wr2[(jb+jj)*320 + col]);
    } else {
        int c2 = c - 2560;
        const float* src;
        if      (c2 <  512){ src = Wls; }
        else if (c2 < 1024){ src = Wlv; c2 -= 512; }
        else if (c2 < 1536){ src = Wis; c2 -= 1024; }
        else if (c2 < 2048){ src = Wiv; c2 -= 1536; }
        else if (c2 < 2560){ src = Wps; c2 -= 2048; }
        else if (c2 < 3072){ src = Wpv; c2 -= 2560; }
        else if (c2 < 8192){ src = Wss; c2 -= 3072; }
        else               { src = Wsv; c2 -= 8192; }
        const int grp = c2 >> 9, loc = c2 & 511;
        const int nt = loc >> 7, ks = (loc >> 6) & 1, ln = loc & 63;
        const int col  = nt*16 + (ln & 15);
        const int row0 = grp*64 + ks*32 + ((ln>>4)&3)*8;
        #pragma unroll
        for (int jj = 0; jj < 8; ++jj) t[jj] = f2b(src[(row0+jj)*64 + col]);
    }
    unsigned* d = (unsigned*)(P + (size_t)c*8);
    d[0] = (unsigned)t[0] | ((unsigned)t[1]<<16);
    d[1] = (unsigned)t[2] | ((unsigned)t[3]<<16);
    d[2] = (unsigned)t[4] | ((unsigned)t[5]<<16);
    d[3] = (unsigned)t[6] | ((unsigned)t[7]<<16);
}

// ---- edge-degree histogram ---------------------------------------------------------------
__global__ __launch_bounds__(256) void khist(
    const int* __restrict__ receivers, int* __restrict__ deg)
{
    const int e = blockIdx.x*256 + threadIdx.x;
    if (e < NEDGES) atomicAdd(&deg[receivers[e]], 1);
}

// ---- counting-sort + materialize sorted edge streams ------------------------------------
__global__ __launch_bounds__(256) void kgather(
    const float* __restrict__ ef, const float* __restrict__ Y1,
    const int* __restrict__ senders, const int* __restrict__ receivers,
    int* __restrict__ cursor,
    unsigned short* __restrict__ efs, float* __restrict__ ys,
    int* __restrict__ snds, int* __restrict__ rcvs)
{
    const int e = blockIdx.x*256 + threadIdx.x;
    if (e >= NEDGES) return;
    const int r = receivers[e];
    const int p = atomicAdd(&cursor[r], 1);
    float4v a = *(const float4v*)&ef[e*8];
    float4v b = *(const float4v*)&ef[e*8 + 4];
    float t[8];
    #pragma unroll
    for (int j = 0; j < 4; ++j){ t[j] = a[j]; t[4+j] = b[j]; }
    *(short8*)&efs[p*8] = pack8(t);
    ys[p*3+0] = Y1[e*3+0];
    ys[p*3+1] = Y1[e*3+1];
    ys[p*3+2] = Y1[e*3+2];
    snds[p] = senders[e];
    rcvs[p] = r;
}

// ---- Kernel A (MFMA): zero Ah + s1/v1 GEMM; block 313 = deg->cursor exclusive scan ------
__global__ __launch_bounds__(256) void knodeA2(
    const float* __restrict__ s, const float* __restrict__ v,
    const unsigned short* __restrict__ P,
    unsigned short* __restrict__ s1, unsigned short* __restrict__ v1,
    float4v* __restrict__ AhZ,
    const int* __restrict__ deg, int* __restrict__ cursor)
{
    if (blockIdx.x == 313){
        __shared__ int lsum[256], loff[256];
        const int t = threadIdx.x;
        const int start = t*79;
        const int end = (start + 79 < NNODES) ? start + 79 : NNODES;
        int sum = 0;
        for (int i = start; i < end; ++i) sum += deg[i];
        lsum[t] = sum;
        __syncthreads();
        if (t == 0){
            int run = 0;
            for (int k = 0; k < 256; ++k){ loff[k] = run; run += lsum[k]; }
        }
        __syncthreads();
        int run = loff[t];
        for (int i = start; i < end; ++i){ cursor[i] = run; run += deg[i]; }
        return;
    }
    float4v zz = {0.f,0.f,0.f,0.f};
    for (int i = blockIdx.x*256 + threadIdx.x; i < NNODES*32; i += 313*256) AhZ[i] = zz;

    const int w = threadIdx.x >> 6, lane = threadIdx.x & 63;
    const int t = blockIdx.x*4 + w;
    if (t >= 1250) return;
    const int mcol = lane & 15, quad = lane >> 4;
    const int node = t*16 + mcol;
    const short8* PB = (const short8*)P;

    short8 fS[2], fV[3][2];
    #pragma unroll
    for (int ks = 0; ks < 2; ++ks){
        const int k0 = ks*32 + quad*8;
        float ts[8];
        { float4v a = *(const float4v*)&s[node*64 + k0];
          float4v b = *(const float4v*)&s[node*64 + k0 + 4];
          #pragma unroll
          for (int j = 0; j < 4; ++j){ ts[j] = a[j]; ts[4+j] = b[j]; } }
        fS[ks] = pack8(ts);
        float tv[24];
        #pragma unroll
        for (int q = 0; q < 6; ++q){
            float4v x = *(const float4v*)&v[(node*64 + k0)*3 + q*4];
            #pragma unroll
            for (int j = 0; j < 4; ++j) tv[q*4+j] = x[j];
        }
        #pragma unroll
        for (int c = 0; c < 3; ++c){
            float tc[8];
            #pragma unroll
            for (int j = 0; j < 8; ++j) tc[j] = tv[j*3 + c];
            fV[c][ks] = pack8(tc);
        }
    }
    float4v z = {0.f,0.f,0.f,0.f};
    #pragma unroll
    for (int nt = 0; nt < 4; ++nt){
        float4v aS = __builtin_amdgcn_mfma_f32_16x16x32_bf16(fS[0], PB[CWls+(nt*2+0)*64+lane], z, 0,0,0);
        aS = __builtin_amdgcn_mfma_f32_16x16x32_bf16(fS[1], PB[CWls+(nt*2+1)*64+lane], aS, 0,0,0);
        float4v aV[3];
        #pragma unroll
        for (int c = 0; c < 3; ++c){
            aV[c] = __builtin_amdgcn_mfma_f32_16x16x32_bf16(fV[c][0], PB[CWlv+(nt*2+0)*64+lane], z, 0,0,0);
            aV[c] = __builtin_amdgcn_mfma_f32_16x16x32_bf16(fV[c][1], PB[CWlv+(nt*2+1)*64+lane], aV[c], 0,0,0);
        }
        const int g = nt*16 + mcol;
        #pragma unroll
        for (int r = 0; r < 4; ++r){
            const int nr = t*16 + quad*4 + r;
            s1[nr*64 + g] = f2b(aS[r]);
            #pragma unroll
            for (int c = 0; c < 3; ++c) v1[(nr*3+c)*64 + g] = f2b(aV[c][r]);
        }
    }
}

// ---- Kernel B (R10): kedge2 shape, sorted coalesced inputs, segmented flush -------------
__global__ __launch_bounds__(256) void kedge4(
    const unsigned short* __restrict__ efs, const float* __restrict__ ys,
    const int* __restrict__ snds, const int* __restrict__ rcvs,
    const float* __restrict__ Wr1, const unsigned short* __restrict__ W2s,
    const unsigned short* __restrict__ s1, const unsigned short* __restrict__ v1,
    half2v* __restrict__ Ah)
{
    __shared__ unsigned short hlds[64*72];
    __shared__ unsigned short twlds[64*330];
    const int lane = threadIdx.x & 63;
    const int w    = threadIdx.x >> 6;
    const int ew   = blockIdx.x*64 + w*16;    // this wave's 16 sorted edges

    float ef0 = b2f(efs[ew*8 + lane]);        // edges ew..ew+7
    float ef1 = b2f(efs[ew*8 + 64 + lane]);   // edges ew+8..ew+15
    float w1r[8];
    #pragma unroll
    for (int r = 0; r < 8; ++r) w1r[r] = Wr1[r*64 + lane];
    float yreg  = (lane < 48) ? ys[ew*3 + lane] : 0.f;
    int sndreg  = (lane < 16) ? snds[ew + lane] : 0;
    int rcvreg  = (lane < 16) ? rcvs[ew + lane] : 0;
    #pragma unroll
    for (int e16 = 0; e16 < 16; ++e16){
        float src = (e16 < 8) ? ef0 : ef1;
        float hj = 0.f;
        #pragma unroll
        for (int r = 0; r < 8; ++r) hj += __shfl(src, (e16&7)*8 + r) * w1r[r];
        hj = hj / (1.f + __expf(-hj));
        hlds[(w*16 + e16)*72 + lane] = f2b(hj);
    }
    __syncthreads();

    short8 a0 = *(const short8*)&hlds[(w*16 + (lane&15))*72 +      (lane>>4)*8];
    short8 a1 = *(const short8*)&hlds[(w*16 + (lane&15))*72 + 32 + (lane>>4)*8];
    float4v acc[20];
    #pragma unroll
    for (int nt = 0; nt < 20; ++nt){
        short8 b0 = *(const short8*)&W2s[((nt*2+0)*64 + lane)*8];
        short8 b1 = *(const short8*)&W2s[((nt*2+1)*64 + lane)*8];
        float4v z = {0.f, 0.f, 0.f, 0.f};
        acc[nt] = __builtin_amdgcn_mfma_f32_16x16x32_bf16(a0, b0, z, 0, 0, 0);
        acc[nt] = __builtin_amdgcn_mfma_f32_16x16x32_bf16(a1, b1, acc[nt], 0, 0, 0);
    }
    #pragma unroll
    for (int nt = 0; nt < 20; ++nt){
        const int col = nt*16 + (lane & 15);
        #pragma unroll
        for (int r = 0; r < 4; ++r){
            const int erow = w*16 + (lane>>4)*4 + r;
            twlds[erow*330 + col] = f2b(acc[nt][r]);
        }
    }

    // TP + segmented accumulate (sorted: rcv changes rarely within the 16)
    int cur = -1;
    float aS = 0.f, av0 = 0.f, av1 = 0.f, av2 = 0.f;
    for (int e16 = 0; e16 < 16; ++e16){
        const int erow = w*16 + e16;
        float tw0 = b2f(twlds[erow*330 +   0 + lane]);
        float tw1 = b2f(twlds[erow*330 +  64 + lane]);
        float tw2 = b2f(twlds[erow*330 + 128 + lane]);
        float tw3 = b2f(twlds[erow*330 + 192 + lane]);
        float tw4 = b2f(twlds[erow*330 + 256 + lane]);
        const int snd = __shfl(sndreg, e16);
        const int rcv = __shfl(rcvreg, e16);
        float y0 = __shfl(yreg, e16*3+0);
        float y1 = __shfl(yreg, e16*3+1);
        float y2 = __shfl(yreg, e16*3+2);
        float ss  = b2f(s1[snd*64 + lane]);
        float vs0 = b2f(v1[(snd*3+0)*64 + lane]);
        float vs1 = b2f(v1[(snd*3+1)*64 + lane]);
        float vs2 = b2f(v1[(snd*3+2)*64 + lane]);
        float dot = vs0*y0 + vs1*y1 + vs2*y2;
        float c0 = vs1*y2 - vs2*y1;
        float c1 = vs2*y0 - vs0*y2;
        float c2 = vs0*y1 - vs1*y0;
        float ms  = tw0*ss + tw1*dot*kINV_SQRT3;
        float t2s = tw2*ss, t4 = tw4*kINV_SQRT2;
        float mv0 = t2s*y0 + tw3*vs0 + t4*c0;
        float mv1 = t2s*y1 + tw3*vs1 + t4*c1;
        float mv2 = t2s*y2 + tw3*vs2 + t4*c2;
        if (rcv != cur){
            if (cur >= 0){
                half2v p01 = { (_Float16)aS,  (_Float16)av0 };
                half2v p23 = { (_Float16)av1, (_Float16)av2 };
                __builtin_amdgcn_global_atomic_fadd_v2f16(&Ah[cur*128 + lane],      p01);
                __builtin_amdgcn_global_atomic_fadd_v2f16(&Ah[cur*128 + 64 + lane], p23);
            }
            cur = rcv; aS = ms; av0 = mv0; av1 = mv1; av2 = mv2;
        } else {
            aS += ms; av0 += mv0; av1 += mv1; av2 += mv2;
        }
    }
    half2v p01 = { (_Float16)aS,  (_Float16)av0 };
    half2v p23 = { (_Float16)av1, (_Float16)av2 };
    __builtin_amdgcn_global_atomic_fadd_v2f16(&Ah[cur*128 + lane],      p01);
    __builtin_amdgcn_global_atomic_fadd_v2f16(&Ah[cur*128 + 64 + lane], p23);
}

// ---- Kernel C (MFMA, species-sorted tiles; vectorized gathers) --------------------------
__global__ __launch_bounds__(256) void knodeC2(
    const float* __restrict__ s, const float* __restrict__ v,
    const half2v* __restrict__ Ah,
    const unsigned short* __restrict__ P,
    const int* __restrict__ perm, const int* __restrict__ tspec,
    const float* __restrict__ wps, const float* __restrict__ wpv,
    const float* __restrict__ Wread,
    float* __restrict__ out)
{
    __shared__ unsigned short Bt[4][4][16*72];
    const int w = threadIdx.x >> 6, lane = threadIdx.x & 63;
    const int t = blockIdx.x*4 + w;
    if (t >= NTILES) return;
    const int mcol = lane & 15, quad = lane >> 4;
    const int spec = tspec[t];
    const int nA   = perm[t*16 + mcol];
    const short8* PB = (const short8*)P;
    const int sb = CWss + spec*512, vb = CWsv + spec*512;

    short8 fAs[2], fAv[3][2], fS[2], fV[3][2];
    if (nA >= 0){
        #pragma unroll
        for (int ks = 0; ks < 2; ++ks){
            const int k0 = ks*32 + quad*8;
            half2v pa[8], pb[8];
            *(float4v*)&pa[0] = *(const float4v*)&Ah[nA*128 + k0];
            *(float4v*)&pa[4] = *(const float4v*)&Ah[nA*128 + k0 + 4];
            *(float4v*)&pb[0] = *(const float4v*)&Ah[nA*128 + 64 + k0];
            *(float4v*)&pb[4] = *(const float4v*)&Ah[nA*128 + 64 + k0 + 4];
            float as_[8], a0_[8], a1_[8], a2_[8];
            #pragma unroll
            for (int j = 0; j < 8; ++j){
                as_[j] = (float)pa[j].x; a0_[j] = (float)pa[j].y;
                a1_[j] = (float)pb[j].x; a2_[j] = (float)pb[j].y;
            }
            fAs[ks] = pack8(as_); fAv[0][ks] = pack8(a0_);
            fAv[1][ks] = pack8(a1_); fAv[2][ks] = pack8(a2_);
            float ts[8];
            { float4v a = *(const float4v*)&s[nA*64 + k0];
              float4v b = *(const float4v*)&s[nA*64 + k0 + 4];
              #pragma unroll
              for (int j = 0; j < 4; ++j){ ts[j] = a[j]; ts[4+j] = b[j]; } }
            fS[ks] = pack8(ts);
            float tv[24];
            #pragma unroll
            for (int q = 0; q < 6; ++q){
                float4v x = *(const float4v*)&v[(nA*64 + k0)*3 + q*4];
                #pragma unroll
                for (int j = 0; j < 4; ++j) tv[q*4+j] = x[j];
            }
            #pragma unroll
            for (int c = 0; c < 3; ++c){
                float tc[8];
                #pragma unroll
                for (int j = 0; j < 8; ++j) tc[j] = tv[j*3 + c];
                fV[c][ks] = pack8(tc);
            }
        }
    } else {
        short8 z8 = {};
        #pragma unroll
        for (int ks = 0; ks < 2; ++ks){
            fAs[ks] = z8; fS[ks] = z8;
            #pragma unroll
            for (int c = 0; c < 3; ++c){ fAv[c][ks] = z8; fV[c][ks] = z8; }
        }
    }

    float4v z = {0.f,0.f,0.f,0.f};
    float4v scS[4], scV[3][4];
    #pragma unroll
    for (int nt = 0; nt < 4; ++nt){
        float4v Ais = __builtin_amdgcn_mfma_f32_16x16x32_bf16(fAs[0], PB[CWis+(nt*2+0)*64+lane], z, 0,0,0);
        Ais = __builtin_amdgcn_mfma_f32_16x16x32_bf16(fAs[1], PB[CWis+(nt*2+1)*64+lane], Ais, 0,0,0);
        float4v Aiv[3];
        #pragma unroll
        for (int c = 0; c < 3; ++c){
            Aiv[c] = __builtin_amdgcn_mfma_f32_16x16x32_bf16(fAv[c][0], PB[CWiv+(nt*2+0)*64+lane], z, 0,0,0);
            Aiv[c] = __builtin_amdgcn_mfma_f32_16x16x32_bf16(fAv[c][1], PB[CWiv+(nt*2+1)*64+lane], Aiv[c], 0,0,0);
        }
        scS[nt] = __builtin_amdgcn_mfma_f32_16x16x32_bf16(fS[0], PB[sb+(nt*2+0)*64+lane], z, 0,0,0);
        scS[nt] = __builtin_amdgcn_mfma_f32_16x16x32_bf16(fS[1], PB[sb+(nt*2+1)*64+lane], scS[nt], 0,0,0);
        #pragma unroll
        for (int c = 0; c < 3; ++c){
            scV[c][nt] = __builtin_amdgcn_mfma_f32_16x16x32_bf16(fV[c][0], PB[vb+(nt*2+0)*64+lane], z, 0,0,0);
            scV[c][nt] = __builtin_amdgcn_mfma_f32_16x16x32_bf16(fV[c][1], PB[vb+(nt*2+1)*64+lane], scV[c][nt], 0,0,0);
        }
        const int g = nt*16 + mcol;
        float w0 = wps[spec*320 +   0 + g], w1 = wps[spec*320 +  64 + g];
        float w2 = wps[spec*320 + 128 + g], w3 = wps[spec*320 + 192 + g];
        float w4 = wps[spec*320 + 256 + g];
        float u0 = wpv[spec*256 +   0 + g], u1 = wpv[spec*256 +  64 + g];
        float u2 = wpv[spec*256 + 128 + g], u3 = wpv[spec*256 + 192 + g];
        #pragma unroll
        for (int r = 0; r < 4; ++r){
            float A  = Ais[r]    * kINV_AVG;
            float a0 = Aiv[0][r] * kINV_AVG;
            float a1 = Aiv[1][r] * kINV_AVG;
            float a2 = Aiv[2][r] * kINV_AVG;
            float d   = a0*a0 + a1*a1 + a2*a2;
            float as2 = A*A;
            float Bs  = w0*A + w1*as2 + w2*d + w3*as2*A + w4*A*d;
            float gg  = u0 + u1*A + u2*as2 + u3*d;
            const int row = quad*4 + r;
            Bt[w][0][row*72 + g] = f2b(Bs);
            Bt[w][1][row*72 + g] = f2b(gg*a0);
            Bt[w][2][row*72 + g] = f2b(gg*a1);
            Bt[w][3][row*72 + g] = f2b(gg*a2);
        }
    }

    short8 bS[2], bV[3][2];
    #pragma unroll
    for (int ks = 0; ks < 2; ++ks){
        bS[ks] = *(const short8*)&Bt[w][0][mcol*72 + ks*32 + quad*8];
        #pragma unroll
        for (int c = 0; c < 3; ++c)
            bV[c][ks] = *(const short8*)&Bt[w][1+c][mcol*72 + ks*32 + quad*8];
    }

    float* out_node = out;
    float* out_s    = out + NNODES;
    float* out_v    = out + NNODES + NNODES*64;
    int ndr[4];
    #pragma unroll
    for (int r = 0; r < 4; ++r) ndr[r] = perm[t*16 + quad*4 + r];
    float4v rd = {0.f,0.f,0.f,0.f};
    #pragma unroll
    for (int nt = 0; nt < 4; ++nt){
        float4v oS = scS[nt];
        oS = __builtin_amdgcn_mfma_f32_16x16x32_bf16(bS[0], PB[CWps+(nt*2+0)*64+lane], oS, 0,0,0);
        oS = __builtin_amdgcn_mfma_f32_16x16x32_bf16(bS[1], PB[CWps+(nt*2+1)*64+lane], oS, 0,0,0);
        float4v oV[3];
        #pragma unroll
        for (int c = 0; c < 3; ++c){
            oV[c] = scV[c][nt];
            oV[c] = __builtin_amdgcn_mfma_f32_16x16x32_bf16(bV[c][0], PB[CWpv+(nt*2+0)*64+lane], oV[c], 0,0,0);
            oV[c] = __builtin_amdgcn_mfma_f32_16x16x32_bf16(bV[c][1], PB[CWpv+(nt*2+1)*64+lane], oV[c], 0,0,0);
        }
        const int g = nt*16 + mcol;
        float wr = Wread[g];
        #pragma unroll
        for (int r = 0; r < 4; ++r){
            if (ndr[r] >= 0){
                out_s[ndr[r]*64 + g] = oS[r];
                #pragma unroll
                for (int c = 0; c < 3; ++c) out_v[(ndr[r]*64 + g)*3 + c] = oV[c][r];
            }
            rd[r] += oS[r] * wr;
        }
    }
    #pragma unroll
    for (int off = 1; off < 16; off <<= 1){
        #pragma unroll
        for (int r = 0; r < 4; ++r) rd[r] += __shfl_xor(rd[r], off);
    }
    if (mcol == 0){
        #pragma unroll
        for (int r = 0; r < 4; ++r) if (ndr[r] >= 0) out_node[ndr[r]] = rd[r];
    }
}

extern "C" void kernel_launch(void* const* d_in, const int* in_sizes, int n_in,
                              void* d_out, int out_size, void* d_ws, size_t ws_size,
                              hipStream_t stream)
{
    (void)in_sizes; (void)n_in; (void)out_size; (void)ws_size;
    const float* s    = (const float*)d_in[0];
    const float* v    = (const float*)d_in[1];
    const float* Y1   = (const float*)d_in[2];
    const float* ef   = (const float*)d_in[3];
    const int* specie = (const int*)d_in[4];
    const int* senders   = (const int*)d_in[5];
    const int* receivers = (const int*)d_in[6];
    const float* Wls  = (const float*)d_in[7];
    const float* Wlv  = (const float*)d_in[8];
    const float* Wss  = (const float*)d_in[9];
    const float* Wsv  = (const float*)d_in[10];
    const float* Wr1  = (const float*)d_in[11];
    const float* Wr2  = (const float*)d_in[12];
    const float* Wis  = (const float*)d_in[13];
    const float* Wiv  = (const float*)d_in[14];
    const float* wps  = (const float*)d_in[15];
    const float* wpv  = (const float*)d_in[16];
    const float* Wps  = (const float*)d_in[17];
    const float* Wpv  = (const float*)d_in[18];
    const float* Wrd  = (const float*)d_in[19];

    float* out = (float*)d_out;
    // d_out layout during the pipeline (knodeC2 overwrites everything at the end):
    //   bytes [80000, 10320000)    t_s1/t_v1 bf16 temporaries (knodeA2 -> kedge4)
    //   bytes [10320000, 20560000) sorted edge streams (kgather -> kedge4):
    //       efs bf16[E*8] (5.12MB) | ys f32[E*3] (3.84MB) | snds i32[E] (1.28MB)
    unsigned short* t_s1 = (unsigned short*)(out + NNODES);
    unsigned short* t_v1 = t_s1 + NNODES*64;
    char* tail = (char*)d_out + 10320000;
    unsigned short* efs = (unsigned short*)tail;
    float* ys  = (float*)(tail + 5120000);
    int* snds  = (int*)(tail + 8960000);

    // ws layout (12.03 MB):
    //  [0, 253952)            bf16 fragment pool P
    //  [262144, +10.24M)      Ah fp16 accumulator [N][2][64] half2
    //  [10502144, +80640)     perm[20160]
    //  [10582784, +5040)      tspec[1260]
    //  [10587824, +80000)     deg[20000]
    //  [10667824, +80000)     cursor[20000]
    //  [10747824, +1280000)   rcvs[320000]
    char* ws = (char*)d_ws;
    unsigned short* P = (unsigned short*)ws;
    half2v* Ah  = (half2v*)(ws + 262144);
    int* perm   = (int*)(ws + 10502144);
    int* tspec  = (int*)(ws + 10582784);
    int* deg    = (int*)(ws + 10587824);
    int* cursor = (int*)(ws + 10667824);
    int* rcvs   = (int*)(ws + 10747824);

    kprep<<<63, 256, 0, stream>>>(specie, Wr2, Wls, Wlv, Wis, Wiv, Wps, Wpv, Wss, Wsv,
                                  P, perm, tspec, deg);
    khist<<<1250, 256, 0, stream>>>(receivers, deg);
    knodeA2<<<314, 256, 0, stream>>>(s, v, P, t_s1, t_v1, (float4v*)Ah, deg, cursor);
    kgather<<<1250, 256, 0, stream>>>(ef, Y1, senders, receivers, cursor, efs, ys, snds, rcvs);
    kedge4<<<5000, 256, 0, stream>>>(efs, ys, snds, rcvs, Wr1, P + CW2*8, t_s1, t_v1, Ah);
    knodeC2<<<315, 256, 0, stream>>>(s, v, Ah, P, perm, tspec, wps, wpv, Wrd, out);
}